// Round 12
// baseline (8657.310 us; speedup 1.0000x reference)
//
#include <hip/hip_runtime.h>
#include <stdint.h>
#include <stddef.h>

typedef _Float16 f16;
typedef _Float16 f16x8 __attribute__((ext_vector_type(8)));
typedef float f32x4 __attribute__((ext_vector_type(4)));

#define MFMA16(a, b, c) __builtin_amdgcn_mfma_f32_16x16x32_f16((a), (b), (c), 0, 0, 0)

static constexpr int kB = 64;
static constexpr int kT = 256;
static constexpr int kD = 1024;
static constexpr int kH = 1024;
static constexpr int kG = 4096;
static constexpr int kSlot = 64 * 1024;          // f16 per h slot [128 owner][64 row][8]
static constexpr int kNSlots = kT + 1;
static constexpr size_t kHistE = (size_t)kNSlots * kSlot;

__device__ __forceinline__ float fast_sigmoid(float x) {
  return __builtin_amdgcn_rcpf(1.f + __expf(-x));
}
__device__ __forceinline__ float fast_tanh(float x) {
  x = fminf(9.f, fmaxf(-9.f, x));
  const float e = __expf(2.f * x);
  return (e - 1.f) * __builtin_amdgcn_rcpf(e + 1.f);
}

// ---- x [64][256][1024] f32 -> xp[t][owner=d>>3][b][d&7] f16 ----
__global__ void x_perm_cvt(const float* __restrict__ x, f16* __restrict__ xp) {
  const size_t id = (size_t)blockIdx.x * 256 + threadIdx.x;
  const int d8 = (int)(id & 127) << 3;
  const int b = (int)(id >> 7) & 63;
  const int t = (int)(id >> 13);
  const float* s = x + (((size_t)b * kT + t) << 10) + d8;
  float4 a = *(const float4*)(s);
  float4 c = *(const float4*)(s + 4);
  f16x8 o;
  o[0] = (f16)a.x; o[1] = (f16)a.y; o[2] = (f16)a.z; o[3] = (f16)a.w;
  o[4] = (f16)c.x; o[5] = (f16)c.y; o[6] = (f16)c.z; o[7] = (f16)c.w;
  *(f16x8*)(xp + (size_t)t * kSlot + (size_t)(d8 >> 3) * 512 + b * 8) = o;
}

// ---- transpose+convert 4 layers: [1024][4096] f32 -> [4096][1024] f16 ----
__global__ void transpose_cvt_z(const float* __restrict__ src, f16* __restrict__ dst) {
  __shared__ float tile[32][33];
  const int z = blockIdx.z;
  const int c0 = blockIdx.x * 32;
  const int r0 = blockIdx.y * 32;
  const float* s = src + (size_t)z * kD * kG;
  f16* d = dst + (size_t)z * kG * kD;
  for (int rr = threadIdx.y; rr < 32; rr += 8)
    tile[rr][threadIdx.x] = s[(size_t)(r0 + rr) * kG + c0 + threadIdx.x];
  __syncthreads();
  for (int cc = threadIdx.y; cc < 32; cc += 8)
    d[(size_t)(c0 + cc) * kD + r0 + threadIdx.x] = (f16)tile[threadIdx.x][cc];
}

// ---------------- 2-layer pipelined scan, self-sufficient gate waves ----------
// 256 WGs x 256 thr (4 waves). layerbit = bid&1, wgl = bid>>1 owns 8 units.
// Wave bw handles batch rows [bw*16, +16) END-TO-END: full K=2048 contraction
// (128 MFMAs, weights from LDS), gates, publish, flag, and DIRECT polling of
// the 128 producer flags it needs (flags laid out [bw][wgl] -> one dwordx2
// per lane). No K-split, no per-step __syncthreads, no poller hop.
#define POLLF(PP, TGT)                                                        \
  for (;;) {                                                                  \
    unsigned long long fv;                                                    \
    asm volatile("global_load_dwordx2 %0, %1, off sc0 sc1\n\t"                \
                 "s_waitcnt vmcnt(0)"                                         \
                 : "=v"(fv) : "v"(PP) : "memory");                            \
    if (__all((int)(fv & 0xffffffffu) >= (TGT) && (int)(fv >> 32) >= (TGT)))  \
      break;                                                                  \
  }

// 32 k-steps (K=1024) of one term: A from h slot (hp), B from Cw at kkg0+ii.
#define TERM_LOOP(hp, kkg0, A0, A1)                                           \
  _Pragma("unroll 1")                                                         \
  for (int base = 0; base < 32; base += 8) {                                  \
    f16x8 ha[8];                                                              \
    _Pragma("unroll")                                                         \
    for (int j = 0; j < 8; ++j)                                               \
      ha[j] = *(const f16x8*)((hp) + (size_t)(base + j) * 2048);              \
    _Pragma("unroll")                                                         \
    for (int j = 0; j < 8; ++j) {                                             \
      const int kkg = (kkg0) + base + j;                                      \
      const f16x8 w0 = *(const f16x8*)&Cw[(kkg * 64 + l) * 8];                \
      const f16x8 w1 = *(const f16x8*)&Cw[((4096 + kkg * 64) + l) * 8];       \
      (A0) = MFMA16(ha[j], w0, (A0));                                         \
      (A1) = MFMA16(ha[j], w1, (A1));                                         \
    }                                                                         \
  }

__launch_bounds__(256, 1)
__global__ void lstm_scan2(const f16* __restrict__ below_lo,
                           const f16* __restrict__ Wt_lo, const f16* __restrict__ Ut_lo,
                           const f16* __restrict__ Wt_hi, const f16* __restrict__ Ut_hi,
                           f16* __restrict__ hist_lo, f16* __restrict__ hist_hi,
                           int* __restrict__ flags_lo,   // [4 bw][128 wgl]
                           int* __restrict__ flags_hi,
                           const float* __restrict__ bias_lo,
                           const float* __restrict__ bias_hi,
                           float* __restrict__ out32) {
  __shared__ f16 Cw[8192 * 8];            // 128 KB  [x(2)][kkg(64)][lane(64)][8]
  __shared__ f16 hstage[4][16][8];        // 1 KB

  const int bid = blockIdx.x;
  const int layerbit = bid & 1;
  const int wgl = bid >> 1;
  const int hbase = wgl * 8;
  const int tid = threadIdx.x;
  const int l = tid & 63, bw = tid >> 6;
  const int lr = l & 15, lq = l >> 4;

  const f16* Wt = layerbit ? Wt_hi : Wt_lo;
  const f16* Ut = layerbit ? Ut_hi : Ut_lo;
  f16* own_hist = layerbit ? hist_hi : hist_lo;
  const f16* below_base = layerbit ? (hist_lo + kSlot) : below_lo; // upper: slot t+1
  int* flags_own = layerbit ? flags_hi : flags_lo;
  const float* bias = layerbit ? bias_hi : bias_lo;

  // ---- stage weights slice into LDS (kkg<32 -> W, kkg>=32 -> U) ----
#pragma unroll 1
  for (int ff = 0; ff < 32; ++ff) {
    const int f = ff * 256 + tid;
    const int x = f >> 12, kkg = (f >> 6) & 63, fl = f & 63;
    const int flr = fl & 15, flq = fl >> 4;
    const int r = x * 16 + flr;
    const int grow = (r >> 3) * 1024 + hbase + (r & 7);
    const f16* src = (kkg < 32) ? Wt : Ut;
    *(f16x8*)&Cw[f * 8] =
        *(const f16x8*)(src + (size_t)grow * 1024 + (kkg & 31) * 32 + flq * 8);
  }
  const float bv0 = bias[((lr < 8) ? 0 : 1024) + hbase + (lr & 7)];
  const float bv1 = bias[((lr < 8) ? 2048 : 3072) + hbase + (lr & 7)];
  __syncthreads();

  const int row8 = (bw * 16 + lr) * 8;
  const int brow = bw * 16 + lq * 4;
  const int ugl = hbase + (lr & 7);
  int* fpub = flags_own + bw * 128 + wgl;
  const int* pollo = flags_own + bw * 128 + 2 * l;
  const int* pollb = flags_lo + bw * 128 + 2 * l;     // upper only

  float c_reg[4] = {0.f, 0.f, 0.f, 0.f};

#pragma unroll 1
  for (int t = 0; t < kT; ++t) {
    f32x4 a0 = {}, a1 = {}, b0 = {}, b1 = {};

    if (!layerbit) {
      // below term from xp (always ready), hides outside the own-chain
      const f16* hb = below_base + (size_t)t * kSlot + lq * 512 + row8;
      TERM_LOOP(hb, 0, b0, b1)
      POLLF(pollo, t)
      const f16* ho = own_hist + (size_t)t * kSlot + lq * 512 + row8;
      TERM_LOOP(ho, 32, a0, a1)
    } else {
      // own term first (older flag, usually ready), then the binding below
      POLLF(pollo, t)
      const f16* ho = own_hist + (size_t)t * kSlot + lq * 512 + row8;
      TERM_LOOP(ho, 32, a0, a1)
      POLLF(pollb, t + 1)
      const f16* hb = below_base + (size_t)t * kSlot + lq * 512 + row8;
      TERM_LOOP(hb, 0, b0, b1)
    }

    float hv[4];
#pragma unroll
    for (int j = 0; j < 4; ++j) {
      const float z0 = a0[j] + b0[j] + bv0;
      const float z1 = a1[j] + b1[j] + bv1;
      const float q0 = __shfl_xor(z0, 8);
      const float q1 = __shfl_xor(z1, 8);
      const float zi = (lr & 8) ? q0 : z0;
      const float zf = (lr & 8) ? z0 : q0;
      const float zg = (lr & 8) ? q1 : z1;
      const float zo = (lr & 8) ? z1 : q1;
      const float iv = fast_sigmoid(zi);
      const float fv = fast_sigmoid(zf);
      const float gv = fast_tanh(zg);
      const float ov = fast_sigmoid(zo);
      const float cn = fv * c_reg[j] + iv * gv;
      c_reg[j] = cn;
      hv[j] = ov * fast_tanh(cn);
    }

    // wave-local gather (same-wave LDS, no barrier), coalesced publish
    if (lr < 8) {
#pragma unroll
      for (int j = 0; j < 4; ++j)
        hstage[bw][lq * 4 + j][lr] = (f16)hv[j];
    }
    if (l < 16) {
      const f16x8 hrow = *(const f16x8*)&hstage[bw][l][0];
      f16* dst = own_hist + (size_t)(t + 1) * kSlot +
                 ((size_t)wgl * 64 + bw * 16 + l) * 8;
      asm volatile("global_store_dwordx4 %0, %1, off sc0 sc1"
                   :: "v"(dst), "v"(hrow) : "memory");
    }
    asm volatile("s_waitcnt vmcnt(0)" ::: "memory");
    if (l == 0) {
      const int val = t + 1;
      asm volatile("global_store_dword %0, %1, off sc0 sc1"
                   :: "v"(fpub), "v"(val) : "memory");
    }
    // final output (layer 3 only), off critical path
    if (out32 && layerbit && lr < 8) {
#pragma unroll
      for (int j = 0; j < 4; ++j)
        out32[((size_t)(brow + j) * kT + t) * kH + ugl] = hv[j];
    }
  }
}

// ---------------- host launch ----------------
extern "C" void kernel_launch(void* const* d_in, const int* in_sizes, int n_in,
                              void* d_out, int out_size, void* d_ws, size_t ws_size,
                              hipStream_t stream) {
  (void)in_sizes; (void)n_in; (void)out_size; (void)ws_size;
  const float* x = (const float*)d_in[0];
  const float* Ws = (const float*)d_in[1];
  const float* Us = (const float*)d_in[2];
  const float* bs = (const float*)d_in[3];
  char* ws = (char*)d_ws;

  const size_t kLayerW = (size_t)kG * kD * 2;               // 8 MB
  const size_t kHistB = kHistE * 2;                         // 33,685,504 B
  const size_t WT_OFF = 0;                                  // 32 MB
  const size_t UT_OFF = WT_OFF + 4 * kLayerW;               // 32 MB
  const size_t XP_OFF = UT_OFF + 4 * kLayerW;               // 33.5 MB
  const size_t HH_OFF = XP_OFF + (size_t)kT * kSlot * 2;    // 134.7 MB
  const size_t FL_OFF = HH_OFF + 4 * kHistB;                // 8 KB

  f16* Wt = (f16*)(ws + WT_OFF);
  f16* Ut = (f16*)(ws + UT_OFF);
  f16* xp = (f16*)(ws + XP_OFF);
  int* fl = (int*)(ws + FL_OFF);

  f16* hist[4];
  for (int i = 0; i < 4; ++i) hist[i] = (f16*)(ws + HH_OFF + i * kHistB);

  x_perm_cvt<<<8192, 256, 0, stream>>>(x, xp);
  transpose_cvt_z<<<dim3(kG / 32, kD / 32, 4), dim3(32, 8), 0, stream>>>(Ws, Wt);
  transpose_cvt_z<<<dim3(kG / 32, kD / 32, 4), dim3(32, 8), 0, stream>>>(Us, Ut);
  for (int i = 0; i < 4; ++i)
    hipMemsetAsync(ws + HH_OFF + i * kHistB, 0, (size_t)kSlot * 2, stream);
  hipMemsetAsync(ws + FL_OFF, 0, 4 * 512 * 4, stream);

  // dispatch 1: layers 0 (lower) + 1 (upper)
  lstm_scan2<<<256, 256, 0, stream>>>(
      xp, Wt, Ut, Wt + (size_t)kG * kD, Ut + (size_t)kG * kD,
      hist[0], hist[1], fl, fl + 512,
      bs, bs + kG, (float*)nullptr);
  // dispatch 2: layers 2 (lower, below = hist[1] slots t+1) + 3 (upper)
  lstm_scan2<<<256, 256, 0, stream>>>(
      hist[1] + kSlot, Wt + 2 * (size_t)kG * kD, Ut + 2 * (size_t)kG * kD,
      Wt + 3 * (size_t)kG * kD, Ut + 3 * (size_t)kG * kD,
      hist[2], hist[3], fl + 1024, fl + 1536,
      bs + 2 * kG, bs + 3 * kG, (float*)d_out);
}

// Round 14
// 3248.310 us; speedup vs baseline: 2.6652x; 2.6652x over previous
//
#include <hip/hip_runtime.h>
#include <stdint.h>
#include <stddef.h>

typedef _Float16 f16;
typedef _Float16 f16x8 __attribute__((ext_vector_type(8)));
typedef float f32x4 __attribute__((ext_vector_type(4)));

#define MFMA16(a, b, c) __builtin_amdgcn_mfma_f32_16x16x32_f16((a), (b), (c), 0, 0, 0)

static constexpr int kB = 64;
static constexpr int kT = 256;
static constexpr int kD = 1024;
static constexpr int kH = 1024;
static constexpr int kG = 4096;
static constexpr int kSlot = 64 * 1024;          // f16 per h slot [128 owner][64 row][8]
static constexpr int kNSlots = kT + 1;
static constexpr size_t kHistE = (size_t)kNSlots * kSlot;

__device__ __forceinline__ float fast_sigmoid(float x) {
  return __builtin_amdgcn_rcpf(1.f + __expf(-x));
}
__device__ __forceinline__ float fast_tanh(float x) {
  x = fminf(9.f, fmaxf(-9.f, x));
  const float e = __expf(2.f * x);
  return (e - 1.f) * __builtin_amdgcn_rcpf(e + 1.f);
}

// ---- x [64][256][1024] f32 -> xp[t][owner=d>>3][b][d&7] f16 ----
__global__ void x_perm_cvt(const float* __restrict__ x, f16* __restrict__ xp) {
  const size_t id = (size_t)blockIdx.x * 256 + threadIdx.x;
  const int d8 = (int)(id & 127) << 3;
  const int b = (int)(id >> 7) & 63;
  const int t = (int)(id >> 13);
  const float* s = x + (((size_t)b * kT + t) << 10) + d8;
  float4 a = *(const float4*)(s);
  float4 c = *(const float4*)(s + 4);
  f16x8 o;
  o[0] = (f16)a.x; o[1] = (f16)a.y; o[2] = (f16)a.z; o[3] = (f16)a.w;
  o[4] = (f16)c.x; o[5] = (f16)c.y; o[6] = (f16)c.z; o[7] = (f16)c.w;
  *(f16x8*)(xp + (size_t)t * kSlot + (size_t)(d8 >> 3) * 512 + b * 8) = o;
}

// ---- transpose+convert 4 layers: [1024][4096] f32 -> [4096][1024] f16 ----
__global__ void transpose_cvt_z(const float* __restrict__ src, f16* __restrict__ dst) {
  __shared__ float tile[32][33];
  const int z = blockIdx.z;
  const int c0 = blockIdx.x * 32;
  const int r0 = blockIdx.y * 32;
  const float* s = src + (size_t)z * kD * kG;
  f16* d = dst + (size_t)z * kG * kD;
  for (int rr = threadIdx.y; rr < 32; rr += 8)
    tile[rr][threadIdx.x] = s[(size_t)(r0 + rr) * kG + c0 + threadIdx.x];
  __syncthreads();
  for (int cc = threadIdx.y; cc < 32; cc += 8)
    d[(size_t)(c0 + cc) * kD + r0 + threadIdx.x] = (f16)tile[threadIdx.x][cc];
}

// -------- 2-layer pipelined scan: data-sentinel sync (no flags) --------
// 256 WGs x 1024 thr (16 waves: 4 bw x 4 kw). layerbit=bid&1, wgl=bid>>1.
// h slots [owner(128)][row(64)][unit(8)]; slots 1..256 pre-filled with f16
// NaN (0x7F7F). Consumers poll their OWN 16B fragments with sc0sc1 loads
// until NaN-free (one f16 check per dword guards dword tearing) and use the
// loaded registers directly: detect == load, one RTT. Producers just store
// h (1 dwordx4 sc0sc1 per lane) -- no drain, no flag, no pollers.
// RULE-18 FIX (r13 bug): sched_barrier(0) after the vmcnt(0) asm, else hipcc
// hoists the register-only sentinel check above the waitcnt.
__launch_bounds__(1024, 1)
__global__ void lstm_scan2(const f16* __restrict__ below_lo,
                           const f16* __restrict__ Wt_lo, const f16* __restrict__ Ut_lo,
                           const f16* __restrict__ Wt_hi, const f16* __restrict__ Ut_hi,
                           f16* __restrict__ hist_lo, f16* __restrict__ hist_hi,
                           const float* __restrict__ bias_lo,
                           const float* __restrict__ bias_hi,
                           float* __restrict__ out32) {
  __shared__ f16 Cw[8192 * 8];              // 128 KB
  __shared__ f16 red0h[2][12 * 64 * 4];     // 12 KB (f16 partials, parity dbuf)
  __shared__ f16 red1h[2][12 * 64 * 4];     // 12 KB
  __shared__ f16 hstage[4][16][8];          // 2 KB

  const int bid = blockIdx.x;
  const int layerbit = bid & 1;
  const int wgl = bid >> 1;
  const int hbase = wgl * 8;
  const int tid = threadIdx.x;
  const int l = tid & 63, w = tid >> 6;
  const int lr = l & 15, lq = l >> 4;
  const int bw = w & 3, kw = w >> 2;

  const f16* Wt = layerbit ? Wt_hi : Wt_lo;
  const f16* Ut = layerbit ? Ut_hi : Ut_lo;
  f16* own_hist = layerbit ? hist_hi : hist_lo;
  const f16* below_base = layerbit ? (hist_lo + kSlot) : below_lo; // upper: slot t+1
  const float* bias = layerbit ? bias_hi : bias_lo;

  // ---- stage weights slice into LDS (kkg<32 -> W, kkg>=32 -> U) ----
#pragma unroll
  for (int ff = 0; ff < 8; ++ff) {
    const int f = tid * 8 + ff;
    const int x = f >> 12, kkg = (f >> 6) & 63, fl = f & 63;
    const int flr = fl & 15, flq = fl >> 4;
    const int r = x * 16 + flr;
    const int grow = (r >> 3) * 1024 + hbase + (r & 7);
    const f16* src = (kkg < 32) ? Wt : Ut;
    *(f16x8*)&Cw[f * 8] =
        *(const f16x8*)(src + (size_t)grow * 1024 + (kkg & 31) * 32 + flq * 8);
  }

  float bv0 = 0.f, bv1 = 0.f;
  if (kw == 0) {
    bv0 = bias[((lr < 8) ? 0 : 1024) + hbase + (lr & 7)];
    bv1 = bias[((lr < 8) ? 2048 : 3072) + hbase + (lr & 7)];
  }
  __syncthreads();

  const int brow = bw * 16 + lq * 4;
  const int ugl = hbase + (lr & 7);
  const int row = bw * 16 + lr;
  // lower: kw0/1 read xp (always ready) -> no poll; kw2/3 own h -> poll.
  // upper: all chunks read produced h -> poll.
  const bool needs_poll = layerbit || (kw >= 2);

  float c_reg[4] = {0.f, 0.f, 0.f, 0.f};

#pragma unroll 1
  for (int t = 0; t < kT; ++t) {
    const f16* hsrc = (kw < 2) ? (below_base + (size_t)t * kSlot)
                               : (own_hist + (size_t)t * kSlot);
    const f16* hp = hsrc + (size_t)((kw & 1) * 64 + lq) * 512 + row * 8;

    f16x8 ha[16];
    if (needs_poll) {
      for (;;) {
#pragma unroll
        for (int ii = 0; ii < 16; ++ii)
          asm volatile("global_load_dwordx4 %0, %1, off sc0 sc1"
                       : "=v"(ha[ii]) : "v"(hp + (size_t)ii * 2048) : "memory");
        asm volatile("s_waitcnt vmcnt(0)" ::: "memory");
        __builtin_amdgcn_sched_barrier(0);   // rule-18 fence: no hoist above waitcnt
        bool ok = true;
#pragma unroll
        for (int ii = 0; ii < 16; ++ii) {
#pragma unroll
          for (int e = 0; e < 8; e += 2) {   // one f16 per dword (tearing guard)
            const f16 ev = ha[ii][e];
            const unsigned short bb = __builtin_bit_cast(unsigned short, ev);
            ok = ok && (bb != 0x7F7F);
          }
        }
        if (__all(ok)) break;
      }
    } else {
#pragma unroll
      for (int ii = 0; ii < 16; ++ii)
        ha[ii] = *(const f16x8*)(hp + (size_t)ii * 2048);
    }

    // ---- 32 MFMAs over this wave's 512-wide K chunk ----
    f32x4 acc0 = {}, acc1 = {};
    const int kkb = kw * 16;
#pragma unroll
    for (int ii = 0; ii < 16; ++ii) {
      const f16x8 b0 = *(const f16x8*)&Cw[((kkb + ii) * 64 + l) * 8];
      const f16x8 b1 = *(const f16x8*)&Cw[((4096 + (kkb + ii) * 64) + l) * 8];
      acc0 = MFMA16(ha[ii], b0, acc0);
      acc1 = MFMA16(ha[ii], b1, acc1);
    }

    // ---- kw1..3 partials -> LDS (f16, parity dbuf); single sync ----
    if (kw != 0) {
      const int rb = ((w - 4) * 64 + l) * 4;
#pragma unroll
      for (int j = 0; j < 4; ++j) {
        red0h[t & 1][rb + j] = (f16)acc0[j];
        red1h[t & 1][rb + j] = (f16)acc1[j];
      }
    }
    __syncthreads();

    if (kw == 0) {
      f32x4 s0 = acc0, s1 = acc1;
#pragma unroll
      for (int q = 0; q < 3; ++q) {
        const int rb = ((q * 4 + bw) * 64 + l) * 4;
#pragma unroll
        for (int j = 0; j < 4; ++j) {
          s0[j] += (float)red0h[t & 1][rb + j];
          s1[j] += (float)red1h[t & 1][rb + j];
        }
      }

      float hv[4];
#pragma unroll
      for (int j = 0; j < 4; ++j) {
        const float z0 = s0[j] + bv0;
        const float z1 = s1[j] + bv1;
        const float q0 = __shfl_xor(z0, 8);
        const float q1 = __shfl_xor(z1, 8);
        const float zi = (lr & 8) ? q0 : z0;
        const float zf = (lr & 8) ? z0 : q0;
        const float zg = (lr & 8) ? q1 : z1;
        const float zo = (lr & 8) ? z1 : q1;
        const float iv = fast_sigmoid(zi);
        const float fv = fast_sigmoid(zf);
        const float gv = fast_tanh(zg);
        const float ov = fast_sigmoid(zo);
        const float cn = fv * c_reg[j] + iv * gv;
        c_reg[j] = cn;
        hv[j] = ov * fast_tanh(cn);
      }

      // gather wave's 16 rows x 8 units; publish = 1 dwordx4 sc0sc1 per lane.
      // No drain, no flag: consumers detect the data itself.
      if (lr < 8) {
#pragma unroll
        for (int j = 0; j < 4; ++j)
          hstage[w][lq * 4 + j][lr] = (f16)hv[j];
      }
      if (l < 16) {
        const f16x8 hrow = *(const f16x8*)&hstage[w][l][0];
        f16* dst = own_hist + (size_t)(t + 1) * kSlot +
                   ((size_t)wgl * 64 + bw * 16 + l) * 8;
        asm volatile("global_store_dwordx4 %0, %1, off sc0 sc1"
                     :: "v"(dst), "v"(hrow) : "memory");
      }
      // final output (layer 3 only), off critical path
      if (out32 && layerbit && lr < 8) {
#pragma unroll
        for (int j = 0; j < 4; ++j)
          out32[((size_t)(brow + j) * kT + t) * kH + ugl] = hv[j];
      }
    }
  }
}

// ---------------- host launch ----------------
extern "C" void kernel_launch(void* const* d_in, const int* in_sizes, int n_in,
                              void* d_out, int out_size, void* d_ws, size_t ws_size,
                              hipStream_t stream) {
  (void)in_sizes; (void)n_in; (void)out_size; (void)ws_size;
  const float* x = (const float*)d_in[0];
  const float* Ws = (const float*)d_in[1];
  const float* Us = (const float*)d_in[2];
  const float* bs = (const float*)d_in[3];
  char* ws = (char*)d_ws;

  const size_t kLayerW = (size_t)kG * kD * 2;               // 8 MB
  const size_t kHistB = kHistE * 2;                         // 33,685,504 B
  const size_t WT_OFF = 0;                                  // 32 MB
  const size_t UT_OFF = WT_OFF + 4 * kLayerW;               // 32 MB
  const size_t XP_OFF = UT_OFF + 4 * kLayerW;               // 33.5 MB
  const size_t HH_OFF = XP_OFF + (size_t)kT * kSlot * 2;    // 134.7 MB

  f16* Wt = (f16*)(ws + WT_OFF);
  f16* Ut = (f16*)(ws + UT_OFF);
  f16* xp = (f16*)(ws + XP_OFF);

  f16* hist[4];
  for (int i = 0; i < 4; ++i) hist[i] = (f16*)(ws + HH_OFF + i * kHistB);

  x_perm_cvt<<<8192, 256, 0, stream>>>(x, xp);
  transpose_cvt_z<<<dim3(kG / 32, kD / 32, 4), dim3(32, 8), 0, stream>>>(Ws, Wt);
  transpose_cvt_z<<<dim3(kG / 32, kD / 32, 4), dim3(32, 8), 0, stream>>>(Us, Ut);
  // slot 0 = zeros (initial h); slots 1..256 = f16 NaN sentinel (byte 0x7F)
  for (int i = 0; i < 4; ++i) {
    hipMemsetAsync(ws + HH_OFF + i * kHistB, 0, (size_t)kSlot * 2, stream);
    hipMemsetAsync(ws + HH_OFF + i * kHistB + (size_t)kSlot * 2, 0x7F,
                   (size_t)kT * kSlot * 2, stream);
  }

  // dispatch 1: layers 0 (lower) + 1 (upper)
  lstm_scan2<<<256, 1024, 0, stream>>>(
      xp, Wt, Ut, Wt + (size_t)kG * kD, Ut + (size_t)kG * kD,
      hist[0], hist[1],
      bs, bs + kG, (float*)nullptr);
  // dispatch 2: layers 2 (lower, below = hist[1] slots t+1) + 3 (upper)
  lstm_scan2<<<256, 1024, 0, stream>>>(
      hist[1] + kSlot, Wt + 2 * (size_t)kG * kD, Ut + 2 * (size_t)kG * kD,
      Wt + 3 * (size_t)kG * kD, Ut + 3 * (size_t)kG * kD,
      hist[2], hist[3],
      bs + 2 * kG, bs + 3 * kG, (float*)d_out);
}